// Round 6
// baseline (145.835 us; speedup 1.0000x reference)
//
#include <hip/hip_runtime.h>
#include <hip/hip_bf16.h>

#ifndef __has_builtin
#define __has_builtin(x) 0
#endif

__device__ __forceinline__ float fast_exp2(float x) {
#if __has_builtin(__builtin_amdgcn_exp2f)
  return __builtin_amdgcn_exp2f(x);
#else
  return exp2f(x);
#endif
}
__device__ __forceinline__ float fast_rcp(float x) {
#if __has_builtin(__builtin_amdgcn_rcpf)
  return __builtin_amdgcn_rcpf(x);
#else
  return 1.0f / x;
#endif
}

constexpr int Bsz = 8, QL = 128, KL = 512, DD = 256, UU = 256;
constexpr int PR = 8;                    // rows per proj block
constexpr int DT = 8;                    // d-chunk in proj pipeline
constexpr int SQB = 8;                   // q rows per scores block
constexpr int SKB = 128;                 // k cols per scores block (32/wave)
constexpr int UT = 8;                    // u prefetch depth in scores
constexpr float NEG_INF = -1e6f;
constexpr float C2 = 2.885390081777927f; // 2*log2(e): exp2(C2*x) == exp(2x)

// ---------------------------------------------------------------------------
// Kernel 1: projections, pre-scaled by C2, BOTH outputs transposed:
//   qpT[b][u][q] (row 128), kpT[b][u][k] (row 512).
// thread = u; 8 rows/block; W coalesced + prefetched; fully-masked key
// blocks exit early (scores never reads masked kpT columns).
// ---------------------------------------------------------------------------
__global__ __launch_bounds__(256) void proj_kernel(
    const float* __restrict__ query, const float* __restrict__ key,
    const float* __restrict__ Wq, const float* __restrict__ Wk,
    const int* __restrict__ valid_len,
    float* __restrict__ qpT, float* __restrict__ kpT)
{
  const int u   = threadIdx.x;
  const int blk = blockIdx.x;
  constexpr int QBLKS = Bsz * QL / PR;   // 128
  const bool isQ = blk < QBLKS;
  const int  m0  = isQ ? blk * PR : (blk - QBLKS) * PR;

  int b, r0i;
  if (isQ) { b = m0 / QL; r0i = m0 % QL; }
  else     { b = m0 / KL; r0i = m0 % KL;
             if (r0i >= valid_len[b]) return; }
  const float* __restrict__ in = isQ ? query : key;
  const float* __restrict__ W  = isQ ? Wq : Wk;
  const float* r0 = in + (size_t)m0 * DD;

  float acc[PR];
#pragma unroll
  for (int r = 0; r < PR; ++r) acc[r] = 0.f;

  float  w_c[DT], w_n[DT];
  float4 r_c[PR][2], r_n[PR][2];

#pragma unroll
  for (int j = 0; j < DT; ++j) w_c[j] = W[j * UU + u];
#pragma unroll
  for (int r = 0; r < PR; ++r) {
    r_c[r][0] = *reinterpret_cast<const float4*>(r0 + r * DD);
    r_c[r][1] = *reinterpret_cast<const float4*>(r0 + r * DD + 4);
  }

  for (int d = 0; d < DD; d += DT) {
    const int dn = (d + DT < DD) ? d + DT : 0;
#pragma unroll
    for (int j = 0; j < DT; ++j) w_n[j] = W[(dn + j) * UU + u];
#pragma unroll
    for (int r = 0; r < PR; ++r) {
      r_n[r][0] = *reinterpret_cast<const float4*>(r0 + r * DD + dn);
      r_n[r][1] = *reinterpret_cast<const float4*>(r0 + r * DD + dn + 4);
    }
#pragma unroll
    for (int r = 0; r < PR; ++r) {
      float a = acc[r];
      a = fmaf(r_c[r][0].x, w_c[0], a);
      a = fmaf(r_c[r][0].y, w_c[1], a);
      a = fmaf(r_c[r][0].z, w_c[2], a);
      a = fmaf(r_c[r][0].w, w_c[3], a);
      a = fmaf(r_c[r][1].x, w_c[4], a);
      a = fmaf(r_c[r][1].y, w_c[5], a);
      a = fmaf(r_c[r][1].z, w_c[6], a);
      a = fmaf(r_c[r][1].w, w_c[7], a);
      acc[r] = a;
    }
#pragma unroll
    for (int j = 0; j < DT; ++j) w_c[j] = w_n[j];
#pragma unroll
    for (int r = 0; r < PR; ++r) { r_c[r][0] = r_n[r][0]; r_c[r][1] = r_n[r][1]; }
  }

  float* o = (isQ ? qpT + ((size_t)b * UU + u) * QL + r0i
                  : kpT + ((size_t)b * UU + u) * KL + r0i);
  *reinterpret_cast<float4*>(o) =
      make_float4(acc[0] * C2, acc[1] * C2, acc[2] * C2, acc[3] * C2);
  *reinterpret_cast<float4*>(o + 4) =
      make_float4(acc[4] * C2, acc[5] * C2, acc[6] * C2, acc[7] * C2);
}

// ---------------------------------------------------------------------------
// Kernel 2: scores tile (b, 8q, 128k), trans-dense & barrier-free.
// 512 blocks, 256 threads. Wave w owns the private 32-k strip
// [k0+32w, k0+32w+32); lane = (kk = l&31, qh = l>>5); each lane accumulates
// 4 q-rows for 1 k. Per u: 1 global dword (prefetched, coalesced 128B/wave),
// 1 ds_read_b128 (qv x4), 1 ds_read_b32 (w2), 4 add + 4 exp + 4 rcp + 4 fma
// -> 8 trans insts per ~20 issued (trans-pipe-bound).
// Waves with strip fully masked return after the single staging barrier.
// sc[b][q][k] = -sum_u 2*v_w[u]*rcp(1+exp2(qp+kp)); softmax is shift-
// invariant so the constant sum(v_w) term is dropped. Masked sc never read.
// ---------------------------------------------------------------------------
__global__ __launch_bounds__(256) void scores_kernel(
    const int* __restrict__ valid_len, const float* __restrict__ v_w,
    const float* __restrict__ qpT, const float* __restrict__ kpT,
    float* __restrict__ sc)
{
  __shared__ __align__(16) float qp_s[UU][SQB];   // 8 KB [u][q]
  __shared__ float w2_s[UU];                      // 1 KB

  const int t   = threadIdx.x;
  const int blk = blockIdx.x;
  const int b   = blk & 7;                 // batch fastest: CU gets mixed vlen
  const int qt  = (blk >> 3) & 15;
  const int kt  = blk >> 7;                // 0..3
  const int q0  = qt * SQB, k0 = kt * SKB;
  const int vlen = valid_len[b];

  // stage qp tile [256u][8q] and 2*v_w (single barrier in the kernel)
  w2_s[t] = 2.0f * v_w[t];
  {
    const float* qrow = qpT + ((size_t)b * UU + t) * QL + q0;  // u = t
    *reinterpret_cast<float4*>(&qp_s[t][0]) =
        *reinterpret_cast<const float4*>(qrow);
    *reinterpret_cast<float4*>(&qp_s[t][4]) =
        *reinterpret_cast<const float4*>(qrow + 4);
  }
  __syncthreads();

  const int w  = t >> 6, l = t & 63;
  const int kk = l & 31, qh = l >> 5;      // k-in-strip, q-half (4 rows each)
  const int kw = k0 + 32 * w;              // wave's k base
  if (kw >= vlen) return;                  // fully-masked strip: sc unread

  const float* __restrict__ kptr =
      kpT + (size_t)b * UU * KL + kw + kk; // column kw+kk, u = 0

  float acc0 = 0.f, acc1 = 0.f, acc2 = 0.f, acc3 = 0.f;
  float cur[UT], nxt[UT];
#pragma unroll
  for (int j = 0; j < UT; ++j) cur[j] = kptr[(size_t)j * KL];

  for (int u0 = 0; u0 < UU; u0 += UT) {
    if (u0 + UT < UU) {
#pragma unroll
      for (int j = 0; j < UT; ++j) nxt[j] = kptr[(size_t)(u0 + UT + j) * KL];
    }
#pragma unroll
    for (int j = 0; j < UT; ++j) {
      const float  w2 = w2_s[u0 + j];
      const float4 qv = *reinterpret_cast<const float4*>(&qp_s[u0 + j][4 * qh]);
      const float  kv = cur[j];
      const float e0 = fast_exp2(qv.x + kv);
      const float e1 = fast_exp2(qv.y + kv);
      const float e2 = fast_exp2(qv.z + kv);
      const float e3 = fast_exp2(qv.w + kv);
      acc0 = fmaf(w2, fast_rcp(1.0f + e0), acc0);
      acc1 = fmaf(w2, fast_rcp(1.0f + e1), acc1);
      acc2 = fmaf(w2, fast_rcp(1.0f + e2), acc2);
      acc3 = fmaf(w2, fast_rcp(1.0f + e3), acc3);
    }
#pragma unroll
    for (int j = 0; j < UT; ++j) cur[j] = nxt[j];
  }

  // store 4 rows; lanes of a q-half write 32 consecutive floats (coalesced).
  // k >= vlen entries are never read downstream -> no masking needed here.
  float* srow = sc + ((size_t)b * QL + q0 + 4 * qh) * KL + kw + kk;
  srow[0]      = -acc0;
  srow[KL]     = -acc1;
  srow[2 * KL] = -acc2;
  srow[3 * KL] = -acc3;
}

// ---------------------------------------------------------------------------
// Kernel 3: masked softmax over k + attn@value for tile (b, 8q, 128d).
// 256 blocks; 256 threads. Wave w softmaxes rows {2w, 2w+1} (masked k
// substituted with NEG_INF at load). PV: 16-k chunks, value prefetched one
// chunk ahead; p_s reads are wave-uniform broadcasts.
// ---------------------------------------------------------------------------
__global__ __launch_bounds__(256) void softmax_pv_kernel(
    const float* __restrict__ value, const int* __restrict__ valid_len,
    const float* __restrict__ sc, float* __restrict__ out)
{
  __shared__ __align__(16) float p_s[SQB][KL];   // 16 KB attn weights

  const int t = threadIdx.x;
  const int l = t & 63, w = t >> 6;
  const int blk = blockIdx.x;
  const int b  = blk & 7;
  const int qt = (blk >> 3) & 15;
  const int dh = blk >> 7;
  const int q0 = qt * SQB;
  const int d0 = dh * 128;
  const int vlen = valid_len[b];

#pragma unroll
  for (int r = 0; r < 2; ++r) {
    const int row = 2 * w + r;
    const float* srow = sc + ((size_t)b * QL + q0 + row) * KL;
    const int kb = l * 8;
    float v[8];
#pragma unroll
    for (int j = 0; j < 8; ++j)
      v[j] = (kb + j < vlen) ? srow[kb + j] : NEG_INF;
    float m = v[0];
#pragma unroll
    for (int j = 1; j < 8; ++j) m = fmaxf(m, v[j]);
#pragma unroll
    for (int off = 32; off >= 1; off >>= 1) m = fmaxf(m, __shfl_xor(m, off, 64));
    float s = 0.f;
#pragma unroll
    for (int j = 0; j < 8; ++j) { v[j] = __expf(v[j] - m); s += v[j]; }
#pragma unroll
    for (int off = 32; off >= 1; off >>= 1) s += __shfl_xor(s, off, 64);
    const float inv = fast_rcp(s);       // s >= 1 (max term contributes 1)
#pragma unroll
    for (int j = 0; j < 8; ++j) p_s[row][kb + j] = v[j] * inv;
  }
  __syncthreads();

  const int dl = t & 127, qg = t >> 7;
  const float* __restrict__ vb = value + (size_t)b * KL * DD + d0 + dl;
  float acc[4] = {0.f, 0.f, 0.f, 0.f};
  const int kmax = (vlen + 15) & ~15;    // p_s beyond vlen is exactly 0

  float vc[16], vn[16];
#pragma unroll
  for (int j = 0; j < 16; ++j) vc[j] = vb[(size_t)j * DD];
  for (int k = 0; k < kmax; k += 16) {
    const int kn = (k + 16 < kmax) ? k + 16 : 0;
#pragma unroll
    for (int j = 0; j < 16; ++j) vn[j] = vb[(size_t)(kn + j) * DD];
#pragma unroll
    for (int g = 0; g < 4; ++g) {
#pragma unroll
      for (int q = 0; q < 4; ++q) {
        const float4 a = *reinterpret_cast<const float4*>(&p_s[qg * 4 + q][k + 4 * g]);
        acc[q] = fmaf(a.x, vc[4 * g + 0], fmaf(a.y, vc[4 * g + 1],
                 fmaf(a.z, vc[4 * g + 2], fmaf(a.w, vc[4 * g + 3], acc[q]))));
      }
    }
#pragma unroll
    for (int j = 0; j < 16; ++j) vc[j] = vn[j];
  }
#pragma unroll
  for (int q = 0; q < 4; ++q)
    out[((size_t)b * QL + q0 + qg * 4 + q) * DD + d0 + dl] = acc[q];
}

extern "C" void kernel_launch(void* const* d_in, const int* in_sizes, int n_in,
                              void* d_out, int out_size, void* d_ws, size_t ws_size,
                              hipStream_t stream) {
  const float* query     = (const float*)d_in[0];
  const float* key       = (const float*)d_in[1];
  const float* value     = (const float*)d_in[2];
  const int*   valid_len = (const int*)d_in[3];
  const float* Wq        = (const float*)d_in[4];
  const float* Wk        = (const float*)d_in[5];
  const float* v_w       = (const float*)d_in[6];
  float* out = (float*)d_out;

  float* qpT = (float*)d_ws;                        // B*U*QL floats (1 MB)
  float* kpT = qpT + (size_t)Bsz * UU * QL;         // B*U*KL floats (4 MB)
  float* sc  = kpT + (size_t)Bsz * UU * KL;         // B*QL*KL floats (2 MB)

  const int proj_blocks = (Bsz * QL + Bsz * KL) / PR;   // 640
  proj_kernel<<<proj_blocks, 256, 0, stream>>>(query, key, Wq, Wk, valid_len,
                                               qpT, kpT);

  const int score_blocks = Bsz * (QL / SQB) * (KL / SKB);  // 512
  scores_kernel<<<score_blocks, 256, 0, stream>>>(valid_len, v_w, qpT, kpT, sc);

  const int pv_blocks = Bsz * (QL / SQB) * (DD / 128);     // 256
  softmax_pv_kernel<<<pv_blocks, 256, 0, stream>>>(value, valid_len, sc, out);
}